// Round 5
// baseline (4347.558 us; speedup 1.0000x reference)
//
#include <hip/hip_runtime.h>
#include <hip/hip_bf16.h>

// Per-label stats: out[l*4 + {0,1,2,3}] = {sum, mean, min, max}
// Strategy: order-preserving uint encoding for float min/max so we can use
// integer atomicMin/atomicMax; HW fp32 atomic add for sums; finalize pass
// computes mean and decodes min/max in place.

__device__ __forceinline__ unsigned int encode_f32(float f) {
    unsigned int b = __float_as_uint(f);
    // monotone map: float order -> unsigned order
    return (b & 0x80000000u) ? ~b : (b | 0x80000000u);
}

__device__ __forceinline__ float decode_f32(unsigned int e) {
    unsigned int b = (e & 0x80000000u) ? (e ^ 0x80000000u) : ~e;
    return __uint_as_float(b);
}

__global__ void ls_init(float* __restrict__ out, int L) {
    int i = blockIdx.x * blockDim.x + threadIdx.x;
    if (i < L) {
        unsigned int* uo = (unsigned int*)out;
        out[4 * i + 0] = 0.0f;            // sum
        out[4 * i + 1] = 0.0f;            // mean (placeholder)
        uo[4 * i + 2] = 0xff800000u;      // encode(+inf)  -> min identity
        uo[4 * i + 3] = 0x007fffffu;      // encode(-inf)  -> max identity
    }
}

__global__ void ls_accum(const float4* __restrict__ x4,
                         const int4* __restrict__ lab4,
                         float* __restrict__ out, int nvec) {
    unsigned int* uo = (unsigned int*)out;
    int stride = gridDim.x * blockDim.x;
    for (int i = blockIdx.x * blockDim.x + threadIdx.x; i < nvec; i += stride) {
        float4 v = x4[i];
        int4 l = lab4[i];

        {   // elem 0
            int base = l.x * 4;
            unsigned int e = encode_f32(v.x);
            unsafeAtomicAdd(&out[base + 0], v.x);
            atomicMin(&uo[base + 2], e);
            atomicMax(&uo[base + 3], e);
        }
        {   // elem 1
            int base = l.y * 4;
            unsigned int e = encode_f32(v.y);
            unsafeAtomicAdd(&out[base + 0], v.y);
            atomicMin(&uo[base + 2], e);
            atomicMax(&uo[base + 3], e);
        }
        {   // elem 2
            int base = l.z * 4;
            unsigned int e = encode_f32(v.z);
            unsafeAtomicAdd(&out[base + 0], v.z);
            atomicMin(&uo[base + 2], e);
            atomicMax(&uo[base + 3], e);
        }
        {   // elem 3
            int base = l.w * 4;
            unsigned int e = encode_f32(v.w);
            unsafeAtomicAdd(&out[base + 0], v.w);
            atomicMin(&uo[base + 2], e);
            atomicMax(&uo[base + 3], e);
        }
    }
}

__global__ void ls_finalize(float* __restrict__ out,
                            const int* __restrict__ cnt, int L) {
    int i = blockIdx.x * blockDim.x + threadIdx.x;
    if (i < L) {
        unsigned int* uo = (unsigned int*)out;
        float s = out[4 * i + 0];
        float c = (float)cnt[i];
        c = fmaxf(c, 1.0f);
        out[4 * i + 1] = s / c;
        out[4 * i + 2] = decode_f32(uo[4 * i + 2]);
        out[4 * i + 3] = decode_f32(uo[4 * i + 3]);
    }
}

extern "C" void kernel_launch(void* const* d_in, const int* in_sizes, int n_in,
                              void* d_out, int out_size, void* d_ws, size_t ws_size,
                              hipStream_t stream) {
    const float* x      = (const float*)d_in[0];
    const int*   labels = (const int*)d_in[1];
    const int*   lcount = (const int*)d_in[2];
    int N = in_sizes[0];
    int L = in_sizes[2];

    float* out = (float*)d_out;

    int initBlocks = (L + 255) / 256;
    ls_init<<<initBlocks, 256, 0, stream>>>(out, L);

    int nvec = N / 4;  // N = 33554432, divisible by 4
    int accBlocks = 2048;  // grid-stride; ~8 blocks/CU worth of waves
    ls_accum<<<accBlocks, 256, 0, stream>>>((const float4*)x, (const int4*)labels,
                                            out, nvec);

    ls_finalize<<<initBlocks, 256, 0, stream>>>(out, lcount, L);
}

// Round 10
// 3100.824 us; speedup vs baseline: 1.4021x; 1.4021x over previous
//
#include <hip/hip_runtime.h>
#include <hip/hip_bf16.h>

// Per-label stats out[l*4+{0,1,2,3}] = {sum, mean, min, max}, N=32Mi, L=100K.
//
// Round-5 PMC: direct device-atomic version was atomic-transaction-bound
// (96M atomics -> 3.2GB write-through, 23G atomics/s, VALUBusy 0.17%).
// Fix: two-phase binning. Phase 1 multisplits input into 49 label-range bins
// (2048 labels each) in d_ws with LDS ring staging (coalesced 64-elem flushes,
// only ~0.5M global counter atomics). Phase 2: per (bin,slice) block builds a
// 24KB LDS-private stat table with LDS atomics (CU-local, no fabric), writes
// partials without atomics. Phase 3 reduces 16 partials/label -> out.
// Requires ws >= ~226MB; otherwise falls back to guarded-atomic path.

#define NBINS  49
#define BSHIFT 11
#define BMASK  2047
#define LPB    2048          // labels per bin
#define CAP    128           // LDS ring capacity per bin (pow2)
#define CAPM   127
#define BINCAP 703616u       // per-bin element capacity (mean 687K + ~20 sigma, mult of 64)
#define SLICES 16

__device__ __forceinline__ unsigned int encode_f32(float f) {
    unsigned int b = __float_as_uint(f);
    return (b & 0x80000000u) ? ~b : (b | 0x80000000u);
}
__device__ __forceinline__ float decode_f32(unsigned int e) {
    unsigned int b = (e & 0x80000000u) ? (e ^ 0x80000000u) : ~e;
    return __uint_as_float(b);
}

// ---------------- binned path ----------------

__global__ void ls_zero(unsigned int* __restrict__ gcnt) {
    if (threadIdx.x < NBINS) gcnt[threadIdx.x] = 0u;
}

__global__ __launch_bounds__(256) void ls_scatter(
    const uint2* __restrict__ x2,      // x bits, 2 elements per vector
    const int2*  __restrict__ lab2,
    unsigned int* __restrict__ bx,     // f32-bits plane  [NBINS * BINCAP]
    unsigned short* __restrict__ blab, // u16 local-label plane [NBINS * BINCAP]
    unsigned int* __restrict__ gcnt,
    int nchunk)                        // chunks of 512 elements
{
    __shared__ unsigned int   sx[NBINS * CAP];
    __shared__ unsigned short slab[NBINS * CAP];
    __shared__ unsigned int   s_tail[NBINS];
    __shared__ unsigned int   s_head[NBINS];

    int tid = threadIdx.x;
    if (tid < NBINS) { s_tail[tid] = 0u; s_head[tid] = 0u; }
    __syncthreads();

    int wave = tid >> 6, lane = tid & 63;

    for (int c = blockIdx.x; c < nchunk; c += gridDim.x) {
        int vbase = c * 256 + tid;           // uint2 index (512 elems / chunk)
        uint2 xv = x2[vbase];
        int2  lv = lab2[vbase];

        {   int lab = lv.x; int bin = lab >> BSHIFT;
            unsigned int t = atomicAdd(&s_tail[bin], 1u);
            unsigned int slot = bin * CAP + (t & CAPM);
            sx[slot] = xv.x; slab[slot] = (unsigned short)(lab & BMASK); }
        {   int lab = lv.y; int bin = lab >> BSHIFT;
            unsigned int t = atomicAdd(&s_tail[bin], 1u);
            unsigned int slot = bin * CAP + (t & CAPM);
            sx[slot] = xv.y; slab[slot] = (unsigned short)(lab & BMASK); }
        __syncthreads();

        // flush full groups of 64, coalesced
        for (int bin = wave; bin < NBINS; bin += 4) {
            unsigned int head = s_head[bin];
            unsigned int avail = s_tail[bin] - head;
            unsigned int k = avail >> 6;
            for (unsigned int g = 0; g < k; ++g) {
                unsigned int gb;
                if (lane == 0) gb = atomicAdd(&gcnt[bin], 64u);
                gb = __shfl(gb, 0, 64);
                unsigned int slot = bin * CAP + ((head + g * 64u + lane) & CAPM);
                unsigned int dst  = bin * BINCAP + gb + lane;
                bx[dst]   = sx[slot];
                blab[dst] = slab[slot];
            }
            if (lane == 0 && k) s_head[bin] = head + k * 64u;
        }
        __syncthreads();
    }

    // drain residuals (<64 per bin)
    for (int bin = wave; bin < NBINS; bin += 4) {
        unsigned int head = s_head[bin];
        unsigned int avail = s_tail[bin] - head;
        unsigned int gb = 0;
        if (lane == 0 && avail) gb = atomicAdd(&gcnt[bin], avail);
        gb = __shfl(gb, 0, 64);
        if (lane < avail) {
            unsigned int slot = bin * CAP + ((head + lane) & CAPM);
            unsigned int dst  = bin * BINCAP + gb + lane;
            bx[dst]   = sx[slot];
            blab[dst] = slab[slot];
        }
    }
}

__global__ __launch_bounds__(256) void ls_binstats(
    const unsigned int* __restrict__ bx,
    const unsigned short* __restrict__ blab,
    const unsigned int* __restrict__ gcnt,
    float* __restrict__ partials)      // [NBINS*SLICES][3*LPB]
{
    __shared__ float        ssum[LPB];
    __shared__ unsigned int smn[LPB];
    __shared__ unsigned int smx[LPB];

    int b = blockIdx.x / SLICES;
    int s = blockIdx.x % SLICES;

    for (int j = threadIdx.x; j < LPB; j += 256) {
        ssum[j] = 0.0f; smn[j] = 0xFFFFFFFFu; smx[j] = 0u;
    }
    __syncthreads();

    unsigned int n = gcnt[b];
    unsigned int lo = (unsigned int)(((unsigned long long)n * s) / SLICES);
    unsigned int hi = (unsigned int)(((unsigned long long)n * (s + 1)) / SLICES);

    const unsigned int*   px = bx   + (size_t)b * BINCAP;
    const unsigned short* pl = blab + (size_t)b * BINCAP;

    for (unsigned int i = lo + threadIdx.x; i < hi; i += 256) {
        float x = __uint_as_float(px[i]);
        unsigned short ll = pl[i];
        atomicAdd(&ssum[ll], x);                 // ds_add_f32
        unsigned int e = encode_f32(x);
        atomicMin(&smn[ll], e);
        atomicMax(&smx[ll], e);
    }
    __syncthreads();

    float* pp = partials + (size_t)blockIdx.x * (3 * LPB);
    unsigned int* ppu = (unsigned int*)pp;
    for (int j = threadIdx.x; j < LPB; j += 256) {
        pp[j]            = ssum[j];
        ppu[LPB + j]     = smn[j];
        ppu[2 * LPB + j] = smx[j];
    }
}

__global__ void ls_final(const float* __restrict__ partials,
                         const int* __restrict__ lcount,
                         float* __restrict__ out, int L)
{
    int l = blockIdx.x * blockDim.x + threadIdx.x;
    if (l >= L) return;
    int b = l >> BSHIFT, local = l & BMASK;
    float sum = 0.0f;
    unsigned int mn = 0xFFFFFFFFu, mx = 0u;
    for (int s = 0; s < SLICES; ++s) {
        const float* pp = partials + (size_t)(b * SLICES + s) * (3 * LPB);
        const unsigned int* ppu = (const unsigned int*)pp;
        sum += pp[local];
        unsigned int m0 = ppu[LPB + local];
        unsigned int m1 = ppu[2 * LPB + local];
        mn = (m0 < mn) ? m0 : mn;
        mx = (m1 > mx) ? m1 : mx;
    }
    float c = (float)lcount[l];
    c = fmaxf(c, 1.0f);
    float inf = __uint_as_float(0x7f800000u);
    float fmn = (mn == 0xFFFFFFFFu) ?  inf : decode_f32(mn);
    float fmx = (mx == 0u)          ? -inf : decode_f32(mx);
    float4 r = make_float4(sum, sum / c, fmn, fmx);
    ((float4*)out)[l] = r;
}

// ---------------- fallback path (ws too small): guarded atomics ----------------

__global__ void ls_init(float* __restrict__ out, int L) {
    int i = blockIdx.x * blockDim.x + threadIdx.x;
    if (i < L) {
        unsigned int* uo = (unsigned int*)out;
        out[4 * i + 0] = 0.0f;
        out[4 * i + 1] = 0.0f;
        uo[4 * i + 2] = 0xFFFFFFFFu;   // min identity (encoded domain)
        uo[4 * i + 3] = 0u;            // max identity
    }
}

__global__ void ls_accum_g(const float4* __restrict__ x4,
                           const int4* __restrict__ lab4,
                           float* __restrict__ out, int nvec) {
    volatile unsigned int* uo = (volatile unsigned int*)out;
    unsigned int* uoa = (unsigned int*)out;
    int stride = gridDim.x * blockDim.x;
    for (int i = blockIdx.x * blockDim.x + threadIdx.x; i < nvec; i += stride) {
        float4 v = x4[i];
        int4 l = lab4[i];
        // stale reads are safe: stale_min >= true_min, so skipping when
        // e >= stale_min never loses a true minimum (symmetric for max).
        #define LS_ONE(LL, VV) { int base = (LL) * 4; float val = (VV);          \
            unsafeAtomicAdd(&out[base], val);                                    \
            unsigned int e = encode_f32(val);                                    \
            if (e < uo[base + 2]) atomicMin(&uoa[base + 2], e);                  \
            if (e > uo[base + 3]) atomicMax(&uoa[base + 3], e); }
        LS_ONE(l.x, v.x)
        LS_ONE(l.y, v.y)
        LS_ONE(l.z, v.z)
        LS_ONE(l.w, v.w)
        #undef LS_ONE
    }
}

__global__ void ls_finalize(float* __restrict__ out,
                            const int* __restrict__ cnt, int L) {
    int i = blockIdx.x * blockDim.x + threadIdx.x;
    if (i < L) {
        unsigned int* uo = (unsigned int*)out;
        float s = out[4 * i + 0];
        float c = fmaxf((float)cnt[i], 1.0f);
        out[4 * i + 1] = s / c;
        out[4 * i + 2] = decode_f32(uo[4 * i + 2]);
        out[4 * i + 3] = decode_f32(uo[4 * i + 3]);
    }
}

extern "C" void kernel_launch(void* const* d_in, const int* in_sizes, int n_in,
                              void* d_out, int out_size, void* d_ws, size_t ws_size,
                              hipStream_t stream) {
    const float* x      = (const float*)d_in[0];
    const int*   labels = (const int*)d_in[1];
    const int*   lcount = (const int*)d_in[2];
    int N = in_sizes[0];
    int L = in_sizes[2];
    float* out = (float*)d_out;

    // ws layout
    size_t xplane  = (size_t)NBINS * BINCAP * 4;                 // 137,908,736
    size_t lplane  = (size_t)NBINS * BINCAP * 2;                 //  68,954,368
    size_t cntoff  = xplane + lplane;
    size_t partoff = cntoff + 256;
    size_t partsz  = (size_t)NBINS * SLICES * LPB * 3 * 4;       //  19,267,584
    size_t need    = partoff + partsz;                           // 226,130,944

    if (ws_size >= need) {
        unsigned char* ws = (unsigned char*)d_ws;
        unsigned int*   bx    = (unsigned int*)ws;
        unsigned short* blab  = (unsigned short*)(ws + xplane);
        unsigned int*   gcnt  = (unsigned int*)(ws + cntoff);
        float*          parts = (float*)(ws + partoff);

        ls_zero<<<1, 64, 0, stream>>>(gcnt);

        int nchunk = N / 512;    // 65536
        ls_scatter<<<1024, 256, 0, stream>>>((const uint2*)x, (const int2*)labels,
                                             bx, blab, gcnt, nchunk);

        ls_binstats<<<NBINS * SLICES, 256, 0, stream>>>(bx, blab, gcnt, parts);

        ls_final<<<(L + 255) / 256, 256, 0, stream>>>(parts, lcount, out, L);
    } else {
        int initBlocks = (L + 255) / 256;
        ls_init<<<initBlocks, 256, 0, stream>>>(out, L);
        ls_accum_g<<<2048, 256, 0, stream>>>((const float4*)x, (const int4*)labels,
                                             out, N / 4);
        ls_finalize<<<initBlocks, 256, 0, stream>>>(out, lcount, L);
    }
}

// Round 16
// 669.731 us; speedup vs baseline: 6.4915x; 4.6300x over previous
//
#include <hip/hip_runtime.h>
#include <hip/hip_bf16.h>

// Per-label stats out[l*4+{0,1,2,3}] = {sum, mean, min, max}, N=32Mi, L=100K.
//
// R5 PMC: direct device atomics -> 23G atomics/s, bound. R10 PMC: scatter with
// gcnt reservation atomics -> 524K same-line atomics serialize at ~20ns each
// (2675us, VALUBusy 2.7%, HBM 1.7%). Fix: count-scan-scatter -> ZERO global
// atomics. (A) per-block label histogram, (B) per-bin exclusive scan over
// blocks gives each (block,bin) a private window, (C) LDS-ring scatter flushes
// coalesced 64-elem groups to precomputed offsets, (D) per-(bin,slice) LDS
// stat tables (CU-local ds atomics), (E) gather-reduce.

#define NBINS  49
#define NB     1024          // blocks in count/scatter grids (ghist stride)
#define BSHIFT 11
#define BMASK  2047
#define LPB    2048          // labels per bin
#define CAP    128           // LDS ring capacity per bin (pow2)
#define CAPM   127
#define BINCAP 696320u       // per-bin capacity (mean ~687K + ~11 sigma, mult of 64)
#define SLICES 16

__device__ __forceinline__ unsigned int encode_f32(float f) {
    unsigned int b = __float_as_uint(f);
    return (b & 0x80000000u) ? ~b : (b | 0x80000000u);
}
__device__ __forceinline__ float decode_f32(unsigned int e) {
    unsigned int b = (e & 0x80000000u) ? (e ^ 0x80000000u) : ~e;
    return __uint_as_float(b);
}

// ---------------- A: per-block histogram ----------------

__global__ __launch_bounds__(256) void ls_count(
    const int2* __restrict__ lab2,
    unsigned int* __restrict__ ghist,   // [NBINS][NB]
    int nchunk)
{
    __shared__ unsigned int hist[64];
    if (threadIdx.x < 64) hist[threadIdx.x] = 0u;
    __syncthreads();

    for (int c = blockIdx.x; c < nchunk; c += gridDim.x) {
        int2 lv = lab2[c * 256 + threadIdx.x];
        atomicAdd(&hist[lv.x >> BSHIFT], 1u);
        atomicAdd(&hist[lv.y >> BSHIFT], 1u);
    }
    __syncthreads();
    if (threadIdx.x < NBINS)
        ghist[threadIdx.x * NB + blockIdx.x] = hist[threadIdx.x];
}

// ---------------- B: per-bin exclusive scan over blocks ----------------

__global__ __launch_bounds__(256) void ls_scan(
    const unsigned int* __restrict__ ghist,
    unsigned int* __restrict__ gbase,   // [NBINS][NB]
    unsigned int* __restrict__ gtotal)  // [NBINS]
{
    __shared__ unsigned int spart[256];
    int bin = blockIdx.x, t = threadIdx.x;
    const unsigned int* h = ghist + bin * NB;
    unsigned int v0 = h[t*4], v1 = h[t*4+1], v2 = h[t*4+2], v3 = h[t*4+3];
    spart[t] = v0 + v1 + v2 + v3;
    __syncthreads();
    for (int off = 1; off < 256; off <<= 1) {
        unsigned int x = (t >= off) ? spart[t - off] : 0u;
        __syncthreads();
        spart[t] += x;
        __syncthreads();
    }
    unsigned int excl = (t == 0) ? 0u : spart[t - 1];
    unsigned int* gb = gbase + bin * NB;
    gb[t*4]   = excl;
    gb[t*4+1] = excl + v0;
    gb[t*4+2] = excl + v0 + v1;
    gb[t*4+3] = excl + v0 + v1 + v2;
    if (t == 255) gtotal[bin] = spart[255];
}

// ---------------- C: atomic-free scatter ----------------

__global__ __launch_bounds__(256) void ls_scatter2(
    const uint2* __restrict__ x2,
    const int2*  __restrict__ lab2,
    const unsigned int* __restrict__ gbase,
    unsigned int* __restrict__ bx,      // [NBINS * BINCAP]
    unsigned short* __restrict__ blab,  // [NBINS * BINCAP]
    int nchunk)
{
    __shared__ unsigned int   sx[NBINS * CAP];
    __shared__ unsigned short slab[NBINS * CAP];
    __shared__ unsigned int   s_tail[NBINS];
    __shared__ unsigned int   s_head[NBINS];
    __shared__ unsigned int   s_off[NBINS];   // next global write offset (bin-local)

    int tid = threadIdx.x;
    if (tid < NBINS) {
        s_tail[tid] = 0u; s_head[tid] = 0u;
        s_off[tid]  = gbase[tid * NB + blockIdx.x];
    }
    __syncthreads();

    int wave = tid >> 6, lane = tid & 63;

    for (int c = blockIdx.x; c < nchunk; c += gridDim.x) {
        int vbase = c * 256 + tid;
        uint2 xv = x2[vbase];
        int2  lv = lab2[vbase];

        {   int lab = lv.x; int bin = lab >> BSHIFT;
            unsigned int t = atomicAdd(&s_tail[bin], 1u);
            unsigned int slot = bin * CAP + (t & CAPM);
            sx[slot] = xv.x; slab[slot] = (unsigned short)(lab & BMASK); }
        {   int lab = lv.y; int bin = lab >> BSHIFT;
            unsigned int t = atomicAdd(&s_tail[bin], 1u);
            unsigned int slot = bin * CAP + (t & CAPM);
            sx[slot] = xv.y; slab[slot] = (unsigned short)(lab & BMASK); }
        __syncthreads();

        // flush full groups of 64 to this block's private window — no atomics
        for (int bin = wave; bin < NBINS; bin += 4) {
            unsigned int head  = s_head[bin];
            unsigned int avail = s_tail[bin] - head;
            unsigned int k = avail >> 6;
            unsigned int off = s_off[bin];
            for (unsigned int g = 0; g < k; ++g) {
                unsigned int slot = bin * CAP + ((head + g * 64u + lane) & CAPM);
                unsigned int dst  = bin * BINCAP + off + g * 64u + lane;
                bx[dst]   = sx[slot];
                blab[dst] = slab[slot];
            }
            if (lane == 0 && k) {
                s_off[bin]  = off + k * 64u;
                s_head[bin] = head + k * 64u;
            }
        }
        __syncthreads();
    }

    // drain residuals (<64 per bin)
    for (int bin = wave; bin < NBINS; bin += 4) {
        unsigned int head  = s_head[bin];
        unsigned int avail = s_tail[bin] - head;
        unsigned int off   = s_off[bin];
        if (lane < avail) {
            unsigned int slot = bin * CAP + ((head + lane) & CAPM);
            unsigned int dst  = bin * BINCAP + off + lane;
            bx[dst]   = sx[slot];
            blab[dst] = slab[slot];
        }
    }
}

// ---------------- D: per-(bin,slice) LDS stat tables ----------------

__global__ __launch_bounds__(256) void ls_binstats(
    const unsigned int* __restrict__ bx,
    const unsigned short* __restrict__ blab,
    const unsigned int* __restrict__ gtotal,
    float* __restrict__ partials)      // [NBINS*SLICES][3*LPB]
{
    __shared__ float        ssum[LPB];
    __shared__ unsigned int smn[LPB];
    __shared__ unsigned int smx[LPB];

    int b = blockIdx.x / SLICES;
    int s = blockIdx.x % SLICES;

    for (int j = threadIdx.x; j < LPB; j += 256) {
        ssum[j] = 0.0f; smn[j] = 0xFFFFFFFFu; smx[j] = 0u;
    }
    __syncthreads();

    unsigned int n = gtotal[b];
    unsigned int lo = (unsigned int)(((unsigned long long)n * s) / SLICES);
    unsigned int hi = (unsigned int)(((unsigned long long)n * (s + 1)) / SLICES);

    const unsigned int*   px = bx   + (size_t)b * BINCAP;
    const unsigned short* pl = blab + (size_t)b * BINCAP;

    for (unsigned int i = lo + threadIdx.x; i < hi; i += 256) {
        float x = __uint_as_float(px[i]);
        unsigned short ll = pl[i];
        atomicAdd(&ssum[ll], x);                 // ds_add_f32
        unsigned int e = encode_f32(x);
        atomicMin(&smn[ll], e);
        atomicMax(&smx[ll], e);
    }
    __syncthreads();

    float* pp = partials + (size_t)blockIdx.x * (3 * LPB);
    unsigned int* ppu = (unsigned int*)pp;
    for (int j = threadIdx.x; j < LPB; j += 256) {
        pp[j]            = ssum[j];
        ppu[LPB + j]     = smn[j];
        ppu[2 * LPB + j] = smx[j];
    }
}

// ---------------- E: gather-reduce ----------------

__global__ void ls_final(const float* __restrict__ partials,
                         const int* __restrict__ lcount,
                         float* __restrict__ out, int L)
{
    int l = blockIdx.x * blockDim.x + threadIdx.x;
    if (l >= L) return;
    int b = l >> BSHIFT, local = l & BMASK;
    float sum = 0.0f;
    unsigned int mn = 0xFFFFFFFFu, mx = 0u;
    for (int s = 0; s < SLICES; ++s) {
        const float* pp = partials + (size_t)(b * SLICES + s) * (3 * LPB);
        const unsigned int* ppu = (const unsigned int*)pp;
        sum += pp[local];
        unsigned int m0 = ppu[LPB + local];
        unsigned int m1 = ppu[2 * LPB + local];
        mn = (m0 < mn) ? m0 : mn;
        mx = (m1 > mx) ? m1 : mx;
    }
    float c = (float)lcount[l];
    c = fmaxf(c, 1.0f);
    float inf = __uint_as_float(0x7f800000u);
    float fmn = (mn == 0xFFFFFFFFu) ?  inf : decode_f32(mn);
    float fmx = (mx == 0u)          ? -inf : decode_f32(mx);
    float4 r = make_float4(sum, sum / c, fmn, fmx);
    ((float4*)out)[l] = r;
}

// ---------------- fallback path (ws too small): guarded atomics ----------------

__global__ void ls_init(float* __restrict__ out, int L) {
    int i = blockIdx.x * blockDim.x + threadIdx.x;
    if (i < L) {
        unsigned int* uo = (unsigned int*)out;
        out[4 * i + 0] = 0.0f;
        out[4 * i + 1] = 0.0f;
        uo[4 * i + 2] = 0xFFFFFFFFu;
        uo[4 * i + 3] = 0u;
    }
}

__global__ void ls_accum_g(const float4* __restrict__ x4,
                           const int4* __restrict__ lab4,
                           float* __restrict__ out, int nvec) {
    volatile unsigned int* uo = (volatile unsigned int*)out;
    unsigned int* uoa = (unsigned int*)out;
    int stride = gridDim.x * blockDim.x;
    for (int i = blockIdx.x * blockDim.x + threadIdx.x; i < nvec; i += stride) {
        float4 v = x4[i];
        int4 l = lab4[i];
        #define LS_ONE(LL, VV) { int base = (LL) * 4; float val = (VV);          \
            unsafeAtomicAdd(&out[base], val);                                    \
            unsigned int e = encode_f32(val);                                    \
            if (e < uo[base + 2]) atomicMin(&uoa[base + 2], e);                  \
            if (e > uo[base + 3]) atomicMax(&uoa[base + 3], e); }
        LS_ONE(l.x, v.x)
        LS_ONE(l.y, v.y)
        LS_ONE(l.z, v.z)
        LS_ONE(l.w, v.w)
        #undef LS_ONE
    }
}

__global__ void ls_finalize(float* __restrict__ out,
                            const int* __restrict__ cnt, int L) {
    int i = blockIdx.x * blockDim.x + threadIdx.x;
    if (i < L) {
        unsigned int* uo = (unsigned int*)out;
        float s = out[4 * i + 0];
        float c = fmaxf((float)cnt[i], 1.0f);
        out[4 * i + 1] = s / c;
        out[4 * i + 2] = decode_f32(uo[4 * i + 2]);
        out[4 * i + 3] = decode_f32(uo[4 * i + 3]);
    }
}

extern "C" void kernel_launch(void* const* d_in, const int* in_sizes, int n_in,
                              void* d_out, int out_size, void* d_ws, size_t ws_size,
                              hipStream_t stream) {
    const float* x      = (const float*)d_in[0];
    const int*   labels = (const int*)d_in[1];
    const int*   lcount = (const int*)d_in[2];
    int N = in_sizes[0];
    int L = in_sizes[2];
    float* out = (float*)d_out;

    // ws layout (all offsets 256B-aligned)
    size_t xplane   = (size_t)NBINS * BINCAP * 4;                // 136,478,720
    size_t lplane   = (size_t)NBINS * BINCAP * 2;                //  68,239,360
    size_t ghistoff = xplane + lplane;                           // 204,718,080
    size_t histsz   = (size_t)NBINS * NB * 4;                    //     200,704
    size_t gbaseoff = ghistoff + histsz;
    size_t gtotoff  = gbaseoff + histsz;
    size_t partoff  = gtotoff + 256;
    size_t partsz   = (size_t)NBINS * SLICES * LPB * 3 * 4;      //  19,267,584
    size_t need     = partoff + partsz;                          // ~224.4 MB

    if (ws_size >= need) {
        unsigned char* ws = (unsigned char*)d_ws;
        unsigned int*   bx    = (unsigned int*)ws;
        unsigned short* blab  = (unsigned short*)(ws + xplane);
        unsigned int*   ghist = (unsigned int*)(ws + ghistoff);
        unsigned int*   gbase = (unsigned int*)(ws + gbaseoff);
        unsigned int*   gtot  = (unsigned int*)(ws + gtotoff);
        float*          parts = (float*)(ws + partoff);

        int nchunk = N / 512;    // 65536; NB=1024 blocks -> 64 chunks each

        ls_count<<<NB, 256, 0, stream>>>((const int2*)labels, ghist, nchunk);
        ls_scan<<<NBINS, 256, 0, stream>>>(ghist, gbase, gtot);
        ls_scatter2<<<NB, 256, 0, stream>>>((const uint2*)x, (const int2*)labels,
                                            gbase, bx, blab, nchunk);
        ls_binstats<<<NBINS * SLICES, 256, 0, stream>>>(bx, blab, gtot, parts);
        ls_final<<<(L + 255) / 256, 256, 0, stream>>>(parts, lcount, out, L);
    } else {
        int initBlocks = (L + 255) / 256;
        ls_init<<<initBlocks, 256, 0, stream>>>(out, L);
        ls_accum_g<<<2048, 256, 0, stream>>>((const float4*)x, (const int4*)labels,
                                             out, N / 4);
        ls_finalize<<<initBlocks, 256, 0, stream>>>(out, lcount, L);
    }
}